// Round 9
// baseline (285.423 us; speedup 1.0000x reference)
//
#include <hip/hip_runtime.h>
#include <math.h>

__device__ __forceinline__ float rdlane(float v, int l) {
    return __int_as_float(__builtin_amdgcn_readlane(__float_as_int(v), l));
}

// ---------------- wprep: block0 = conv2 weight transpose, block1 = conv3, block2 = E2
__global__ __launch_bounds__(384) void wprep_k(
    const float* __restrict__ c2w, const float* __restrict__ c3w,
    const float* __restrict__ emb, const float* __restrict__ Wxh,
    const float* __restrict__ bh,
    float* __restrict__ w2t, float* __restrict__ w3t, float* __restrict__ E2)
{
    const int t = threadIdx.x, blk = blockIdx.x;
    if (blk == 0) {
        for (int i = t; i < 9216; i += 384) {
            const int co = i & 31, k = i >> 5;
            w2t[i] = c2w[co * 288 + k];
        }
    } else if (blk == 1) {
        for (int i = t; i < 9216; i += 384) {
            const int co = i & 31, k = i >> 5;
            w3t[i] = c3w[co * 288 + k];
        }
    } else {
        const int o = t >> 7, j = t & 127;
        float a = bh[j], a2 = 0.f;
        #pragma unroll 4
        for (int d = 0; d < 64; ++d) {
            a  += emb[o * 128 + d] * Wxh[d * 128 + j];
            a2 += emb[o * 128 + d + 64] * Wxh[(d + 64) * 128 + j];
        }
        E2[t] = a + a2;
    }
}

// ---------------- conv1: (512,1,32,32) -> conv3x3(32) -> BN -> ReLU -> pool2 -> h1 (512,32,15,15)
__global__ __launch_bounds__(512) void conv1_k(
    const float* __restrict__ x, const float* __restrict__ w,
    const float* __restrict__ cb, const float* __restrict__ bg,
    const float* __restrict__ bb, const float* __restrict__ bm,
    const float* __restrict__ bv, float* __restrict__ h1)
{
    __shared__ float img[32 * 33];
    __shared__ float ws_[288];
    __shared__ float scale[32], bias2[32];
    const int b = blockIdx.x, tid = threadIdx.x;
    for (int i = tid; i < 1024; i += 512) {
        const int y = i >> 5, xx = i & 31;
        img[y * 33 + xx] = x[b * 1024 + i];
    }
    if (tid < 288) ws_[tid] = w[tid];
    if (tid < 32) {
        float inv = bg[tid] / sqrtf(bv[tid] + 1e-5f);
        scale[tid] = inv;
        bias2[tid] = (cb[tid] - bm[tid]) * inv + bb[tid];
    }
    __syncthreads();

    const int co = tid >> 4, py = tid & 15;
    if (py < 15) {
        float acc0[30], acc1[30];
        #pragma unroll
        for (int i = 0; i < 30; ++i) { acc0[i] = 0.f; acc1[i] = 0.f; }
        const float* w9 = &ws_[co * 9];
        #pragma unroll
        for (int ir = 0; ir < 4; ++ir) {
            const int y = 2 * py + ir;
            float wk0 = 0.f, wk1 = 0.f, wk2 = 0.f, wl0 = 0.f, wl1 = 0.f, wl2 = 0.f;
            if (ir <= 2) { wk0 = w9[ir * 3 + 0]; wk1 = w9[ir * 3 + 1]; wk2 = w9[ir * 3 + 2]; }
            if (ir >= 1) { wl0 = w9[(ir - 1) * 3 + 0]; wl1 = w9[(ir - 1) * 3 + 1]; wl2 = w9[(ir - 1) * 3 + 2]; }
            #pragma unroll
            for (int xx = 0; xx < 32; ++xx) {
                const float rv = img[y * 33 + xx];
                if (ir <= 2) {
                    if (xx <= 29) acc0[xx] += rv * wk0;
                    if (xx >= 1 && xx <= 30) acc0[xx - 1] += rv * wk1;
                    if (xx >= 2) acc0[xx - 2] += rv * wk2;
                }
                if (ir >= 1) {
                    if (xx <= 29) acc1[xx] += rv * wl0;
                    if (xx >= 1 && xx <= 30) acc1[xx - 1] += rv * wl1;
                    if (xx >= 2) acc1[xx - 2] += rv * wl2;
                }
            }
        }
        const float sc = scale[co], bs = bias2[co];
        #pragma unroll
        for (int px = 0; px < 15; ++px) {
            const float v = fmaxf(acc0[2 * px] * sc + bs, 0.f)
                          + fmaxf(acc0[2 * px + 1] * sc + bs, 0.f)
                          + fmaxf(acc1[2 * px] * sc + bs, 0.f)
                          + fmaxf(acc1[2 * px + 1] * sc + bs, 0.f);
            h1[b * 7200 + co * 225 + py * 15 + px] = v * 0.25f;
        }
    }
}

// ---------------- conv2 v3: LDS = image only (rows padded to 16 -> aligned b128 reads);
// weights from pre-transposed global w2t (coalesced, L1/L2-hot). 192 thr = (co, py).
__global__ __launch_bounds__(192) void conv2_k(
    const float* __restrict__ h1, const float* __restrict__ w2t,
    const float* __restrict__ cb, const float* __restrict__ bg,
    const float* __restrict__ bb, const float* __restrict__ bm,
    const float* __restrict__ bv, float* __restrict__ h2)
{
    __shared__ float in_s[32 * 14 * 16];      // [ci][row<14][16] (col 15 = pad, unused)
    const int b = blockIdx.x, tid = threadIdx.x;
    for (int i = tid; i < 6720; i += 192) {
        const int ci = i / 210, rem = i % 210;
        const int row = rem / 15, col = rem % 15;
        in_s[ci * 224 + row * 16 + col] = h1[b * 7200 + ci * 225 + rem];
    }
    __syncthreads();

    const int co = tid & 31, py = tid >> 5;   // py 0..5
    float acc0[12], acc1[12];
    #pragma unroll
    for (int i = 0; i < 12; ++i) { acc0[i] = 0.f; acc1[i] = 0.f; }

    for (int ci = 0; ci < 32; ++ci) {
        float w9[9];
        const float* wk = &w2t[(ci * 9) * 32 + co];
        #pragma unroll
        for (int kk = 0; kk < 9; ++kk) w9[kk] = wk[kk * 32];
        #pragma unroll
        for (int ir = 0; ir < 4; ++ir) {
            const float* rp = &in_s[ci * 224 + (2 * py + ir) * 16];
            const float4 q0 = *reinterpret_cast<const float4*>(rp);
            const float4 q1 = *reinterpret_cast<const float4*>(rp + 4);
            const float4 q2 = *reinterpret_cast<const float4*>(rp + 8);
            const float4 q3 = *reinterpret_cast<const float4*>(rp + 12);
            float p[16];
            p[0]=q0.x; p[1]=q0.y; p[2]=q0.z; p[3]=q0.w;
            p[4]=q1.x; p[5]=q1.y; p[6]=q1.z; p[7]=q1.w;
            p[8]=q2.x; p[9]=q2.y; p[10]=q2.z; p[11]=q2.w;
            p[12]=q3.x; p[13]=q3.y; p[14]=q3.z; p[15]=q3.w;
            if (ir <= 2) {
                const float wa0 = w9[ir * 3], wa1 = w9[ir * 3 + 1], wa2 = w9[ir * 3 + 2];
                #pragma unroll
                for (int c = 0; c < 12; ++c)
                    acc0[c] += p[c] * wa0 + p[c + 1] * wa1 + p[c + 2] * wa2;
            }
            if (ir >= 1) {
                const float wb0 = w9[(ir - 1) * 3], wb1 = w9[(ir - 1) * 3 + 1], wb2 = w9[(ir - 1) * 3 + 2];
                #pragma unroll
                for (int c = 0; c < 12; ++c)
                    acc1[c] += p[c] * wb0 + p[c + 1] * wb1 + p[c + 2] * wb2;
            }
        }
    }
    const float inv = bg[co] / sqrtf(bv[co] + 1e-5f);
    const float bs = (cb[co] - bm[co]) * inv + bb[co];
    #pragma unroll
    for (int px = 0; px < 6; ++px) {
        const float v = fmaxf(acc0[2 * px] * inv + bs, 0.f)
                      + fmaxf(acc0[2 * px + 1] * inv + bs, 0.f)
                      + fmaxf(acc1[2 * px] * inv + bs, 0.f)
                      + fmaxf(acc1[2 * px + 1] * inv + bs, 0.f);
        h2[b * 1152 + co * 36 + py * 6 + px] = v * 0.25f;
    }
}

// ---------------- conv3 v3: weights from w3t global; in_s rows padded to 8 (float2 reads)
__global__ __launch_bounds__(256) void conv3_k(
    const float* __restrict__ h2, const float* __restrict__ w3t,
    const float* __restrict__ cb, const float* __restrict__ bg,
    const float* __restrict__ bb, const float* __restrict__ bm,
    const float* __restrict__ bv, float* __restrict__ feat)
{
    __shared__ float in_s[32 * 48];           // [ci][6][8]
    __shared__ float psum[2][4][4][33];
    const int b = blockIdx.x, tid = threadIdx.x;
    for (int i = tid; i < 1152; i += 256) {
        const int ci = i / 36, rem = i % 36;
        const int row = rem / 6, col = rem % 6;
        in_s[ci * 48 + row * 8 + col] = h2[b * 1152 + i];
    }
    __syncthreads();

    const int co = tid & 31, g = tid >> 5;
    const int pos = g & 3, h = g >> 2;
    const int y0 = (pos >> 1) * 2, x0 = (pos & 1) * 2;
    float s00 = 0.f, s01 = 0.f, s10 = 0.f, s11 = 0.f;
    for (int ci = h * 16; ci < h * 16 + 16; ++ci) {
        float w9[9];
        const float* wk = &w3t[(ci * 9) * 32 + co];
        #pragma unroll
        for (int kk = 0; kk < 9; ++kk) w9[kk] = wk[kk * 32];
        const int base = ci * 48 + y0 * 8 + x0;
        float p[4][4];
        #pragma unroll
        for (int i = 0; i < 4; ++i) {
            const float2 a = *reinterpret_cast<const float2*>(&in_s[base + i * 8]);
            const float2 c = *reinterpret_cast<const float2*>(&in_s[base + i * 8 + 2]);
            p[i][0] = a.x; p[i][1] = a.y; p[i][2] = c.x; p[i][3] = c.y;
        }
        #pragma unroll
        for (int ky = 0; ky < 3; ++ky)
            #pragma unroll
            for (int kx = 0; kx < 3; ++kx) {
                const float wv = w9[ky * 3 + kx];
                s00 += p[ky][kx] * wv;
                s01 += p[ky][kx + 1] * wv;
                s10 += p[ky + 1][kx] * wv;
                s11 += p[ky + 1][kx + 1] * wv;
            }
    }
    psum[h][pos][0][co] = s00;
    psum[h][pos][1][co] = s01;
    psum[h][pos][2][co] = s10;
    psum[h][pos][3][co] = s11;
    __syncthreads();
    if (h == 0) {
        const float inv = bg[co] / sqrtf(bv[co] + 1e-5f);
        const float bs = (cb[co] - bm[co]) * inv + bb[co];
        float v = 0.f;
        #pragma unroll
        for (int k = 0; k < 4; ++k) {
            const float sk = psum[0][pos][k][co] + psum[1][pos][k][co];
            v += fmaxf(sk * inv + bs, 0.f);
        }
        feat[b * 128 + co * 4 + pos] = v * 0.25f;
    }
}

// ---------------- router v3: GEMVs use v_readlane from registers (8 ds_reads/step, not 256)
__global__ __launch_bounds__(512, 4) void router_k(
    const float* __restrict__ feat, const float* __restrict__ Whh,
    const float* __restrict__ Who, const float* __restrict__ bo,
    const float* __restrict__ E2, const float* __restrict__ Wexp,
    const float* __restrict__ bexp, const float* __restrict__ Wout,
    const float* __restrict__ bout, float* __restrict__ out)
{
    const int b = blockIdx.x, tid = threadIdx.x;
    const int j = tid & 127, q = tid >> 7, lane31 = tid & 31;
    __shared__ float hbuf[2][8][128];
    __shared__ float E2s[3][128];
    __shared__ float bexps[3][128];
    __shared__ float psum[4][8][128];
    __shared__ float total[24], scores[8];
    __shared__ int bi[8], opsel[8], oph[3][8], oph2[3][8];

    const float fv = feat[b * 128 + j];
    hbuf[0][2 * q][j] = fv;
    hbuf[0][2 * q + 1][j] = fv;
    for (int i = tid; i < 384; i += 512) {
        (&E2s[0][0])[i] = E2[i];
        (&bexps[0][0])[i] = bexp[i];
    }
    if (tid < 8) scores[tid] = (tid == 0) ? 0.f : -1.0e9f;
    __syncthreads();

    const int dbase = q * 32;
    int cur = 0;
    for (int t = 0; t < 3; ++t) {
        // ---- logits + log_softmax(T=0.4)
        {
            const int grp = tid >> 5, l = tid & 31;
            if (grp < 8) {
                float p0 = 0.f, p1 = 0.f, p2 = 0.f;
                #pragma unroll
                for (int dd = 0; dd < 4; ++dd) {
                    const int d = l + 32 * dd;
                    const float hv = hbuf[cur][grp][d];
                    p0 += hv * Who[d * 3 + 0];
                    p1 += hv * Who[d * 3 + 1];
                    p2 += hv * Who[d * 3 + 2];
                }
                #pragma unroll
                for (int s = 16; s > 0; s >>= 1) {
                    p0 += __shfl_down(p0, s, 32);
                    p1 += __shfl_down(p1, s, 32);
                    p2 += __shfl_down(p2, s, 32);
                }
                if (l == 0) {
                    const float t0 = (p0 + bo[0]) / 0.4f;
                    const float t1 = (p1 + bo[1]) / 0.4f;
                    const float t2 = (p2 + bo[2]) / 0.4f;
                    const float mm = fmaxf(t0, fmaxf(t1, t2));
                    const float lse = mm + logf(expf(t0 - mm) + expf(t1 - mm) + expf(t2 - mm));
                    const float sc = scores[grp];
                    total[grp * 3 + 0] = sc + (t0 - lse);
                    total[grp * 3 + 1] = sc + (t1 - lse);
                    total[grp * 3 + 2] = sc + (t2 - lse);
                }
            }
        }
        __syncthreads();
        // ---- stable top-8 (first-index-wins = lax.top_k)
        if (tid == 0) {
            float tv[24];
            #pragma unroll
            for (int i = 0; i < 24; ++i) tv[i] = total[i];
            unsigned mask = 0;
            for (int r = 0; r < 8; ++r) {
                float best = -INFINITY; int idx = 0;
                #pragma unroll
                for (int i = 0; i < 24; ++i) {
                    if (!(mask & (1u << i)) && tv[i] > best) { best = tv[i]; idx = i; }
                }
                mask |= 1u << idx;
                scores[r] = best;
                bi[r] = idx / 3;
                opsel[r] = idx % 3;
            }
            for (int r = 0; r < 8; ++r) {
                for (int s = 0; s < t; ++s) oph2[s][r] = oph[s][bi[r]];
                oph2[t][r] = opsel[r];
            }
            for (int r = 0; r < 8; ++r)
                for (int s = 0; s <= t; ++s) oph[s][r] = oph2[s][r];
        }
        __syncthreads();
        // ---- beam GEMV: h rows (beam-gathered) in regs, readlane broadcast; Whh read once
        {
            const float h0r = hbuf[cur][bi[0]][dbase + lane31];
            const float h1r = hbuf[cur][bi[1]][dbase + lane31];
            const float h2r = hbuf[cur][bi[2]][dbase + lane31];
            const float h3r = hbuf[cur][bi[3]][dbase + lane31];
            const float h4r = hbuf[cur][bi[4]][dbase + lane31];
            const float h5r = hbuf[cur][bi[5]][dbase + lane31];
            const float h6r = hbuf[cur][bi[6]][dbase + lane31];
            const float h7r = hbuf[cur][bi[7]][dbase + lane31];
            float a0 = 0.f, a1 = 0.f, a2 = 0.f, a3 = 0.f, a4 = 0.f, a5 = 0.f, a6 = 0.f, a7 = 0.f;
            const float* wp = &Whh[dbase * 128 + j];
            #pragma unroll
            for (int dd = 0; dd < 32; ++dd) {
                const float wv = wp[dd * 128];
                a0 += rdlane(h0r, dd) * wv; a1 += rdlane(h1r, dd) * wv;
                a2 += rdlane(h2r, dd) * wv; a3 += rdlane(h3r, dd) * wv;
                a4 += rdlane(h4r, dd) * wv; a5 += rdlane(h5r, dd) * wv;
                a6 += rdlane(h6r, dd) * wv; a7 += rdlane(h7r, dd) * wv;
            }
            psum[q][0][j] = a0; psum[q][1][j] = a1; psum[q][2][j] = a2; psum[q][3][j] = a3;
            psum[q][4][j] = a4; psum[q][5][j] = a5; psum[q][6][j] = a6; psum[q][7][j] = a7;
        }
        __syncthreads();
        {
            const int nxt = cur ^ 1;
            #pragma unroll
            for (int rr = 0; rr < 2; ++rr) {
                const int r = 2 * q + rr;
                const float v = psum[0][r][j] + psum[1][r][j] + psum[2][r][j] + psum[3][r][j]
                              + E2s[opsel[r]][j];
                hbuf[nxt][r][j] = tanhf(v);
            }
        }
        cur ^= 1;
        __syncthreads();
    }

    // ---- expert chain
    hbuf[0][2 * q][j] = fv;
    hbuf[0][2 * q + 1][j] = fv;
    __syncthreads();
    int c2 = 0;
    for (int t = 0; t < 3; ++t) {
        {
            const float h0r = hbuf[c2][0][dbase + lane31];
            const float h1r = hbuf[c2][1][dbase + lane31];
            const float h2r = hbuf[c2][2][dbase + lane31];
            const float h3r = hbuf[c2][3][dbase + lane31];
            const float h4r = hbuf[c2][4][dbase + lane31];
            const float h5r = hbuf[c2][5][dbase + lane31];
            const float h6r = hbuf[c2][6][dbase + lane31];
            const float h7r = hbuf[c2][7][dbase + lane31];
            const float* wp0 = &Wexp[oph[t][0] * 16384 + dbase * 128 + j];
            const float* wp1 = &Wexp[oph[t][1] * 16384 + dbase * 128 + j];
            const float* wp2 = &Wexp[oph[t][2] * 16384 + dbase * 128 + j];
            const float* wp3 = &Wexp[oph[t][3] * 16384 + dbase * 128 + j];
            const float* wp4 = &Wexp[oph[t][4] * 16384 + dbase * 128 + j];
            const float* wp5 = &Wexp[oph[t][5] * 16384 + dbase * 128 + j];
            const float* wp6 = &Wexp[oph[t][6] * 16384 + dbase * 128 + j];
            const float* wp7 = &Wexp[oph[t][7] * 16384 + dbase * 128 + j];
            float a0 = 0.f, a1 = 0.f, a2 = 0.f, a3 = 0.f, a4 = 0.f, a5 = 0.f, a6 = 0.f, a7 = 0.f;
            #pragma unroll
            for (int dd = 0; dd < 32; ++dd) {
                a0 += rdlane(h0r, dd) * wp0[dd * 128];
                a1 += rdlane(h1r, dd) * wp1[dd * 128];
                a2 += rdlane(h2r, dd) * wp2[dd * 128];
                a3 += rdlane(h3r, dd) * wp3[dd * 128];
                a4 += rdlane(h4r, dd) * wp4[dd * 128];
                a5 += rdlane(h5r, dd) * wp5[dd * 128];
                a6 += rdlane(h6r, dd) * wp6[dd * 128];
                a7 += rdlane(h7r, dd) * wp7[dd * 128];
            }
            psum[q][0][j] = a0; psum[q][1][j] = a1; psum[q][2][j] = a2; psum[q][3][j] = a3;
            psum[q][4][j] = a4; psum[q][5][j] = a5; psum[q][6][j] = a6; psum[q][7][j] = a7;
        }
        __syncthreads();
        {
            const int nxt = c2 ^ 1;
            #pragma unroll
            for (int rr = 0; rr < 2; ++rr) {
                const int r = 2 * q + rr;
                const float v = psum[0][r][j] + psum[1][r][j] + psum[2][r][j] + psum[3][r][j]
                              + bexps[oph[t][r]][j];
                hbuf[nxt][r][j] = fmaxf(v, 0.f);
            }
        }
        c2 ^= 1;
        __syncthreads();
    }

    // ---- out = log_softmax(hs @ Wout + bout)
    {
        const int grp = tid >> 5, l = tid & 31;
        if (grp < 8) {
            float acc = 0.f;
            if (l < 10) {
                acc = bout[l];
                float acc2 = 0.f;
                const float* hrow = &hbuf[c2][grp][0];
                #pragma unroll 4
                for (int d = 0; d < 64; ++d) {
                    acc  += hrow[d] * Wout[d * 10 + l];
                    acc2 += hrow[d + 64] * Wout[(d + 64) * 10 + l];
                }
                acc += acc2;
            }
            float mm = (l < 10) ? acc : -INFINITY;
            #pragma unroll
            for (int s = 16; s > 0; s >>= 1) mm = fmaxf(mm, __shfl_xor(mm, s, 32));
            float ex = (l < 10) ? expf(acc - mm) : 0.f;
            float sum = ex;
            #pragma unroll
            for (int s = 16; s > 0; s >>= 1) sum += __shfl_xor(sum, s, 32);
            const float lse = mm + logf(sum);
            if (l < 10) out[(b * 8 + grp) * 10 + l] = acc - lse;
        }
    }
}

extern "C" void kernel_launch(void* const* d_in, const int* in_sizes, int n_in,
                              void* d_out, int out_size, void* d_ws, size_t ws_size,
                              hipStream_t stream) {
    (void)in_sizes; (void)n_in; (void)out_size; (void)ws_size;
    const float* x    = (const float*)d_in[0];
    const float* c1w  = (const float*)d_in[1];
    const float* c1b  = (const float*)d_in[2];
    const float* g1   = (const float*)d_in[3];
    const float* b1   = (const float*)d_in[4];
    const float* m1   = (const float*)d_in[5];
    const float* v1   = (const float*)d_in[6];
    const float* c2w  = (const float*)d_in[7];
    const float* c2b  = (const float*)d_in[8];
    const float* g2   = (const float*)d_in[9];
    const float* b2   = (const float*)d_in[10];
    const float* m2   = (const float*)d_in[11];
    const float* v2   = (const float*)d_in[12];
    const float* c3w  = (const float*)d_in[13];
    const float* c3b  = (const float*)d_in[14];
    const float* g3   = (const float*)d_in[15];
    const float* b3   = (const float*)d_in[16];
    const float* m3   = (const float*)d_in[17];
    const float* v3   = (const float*)d_in[18];
    const float* Wxh  = (const float*)d_in[19];
    const float* Whh  = (const float*)d_in[20];
    const float* bh   = (const float*)d_in[21];
    const float* Who  = (const float*)d_in[22];
    const float* bo   = (const float*)d_in[23];
    const float* emb  = (const float*)d_in[24];
    const float* Wexp = (const float*)d_in[25];
    const float* bexp = (const float*)d_in[26];
    const float* Wout = (const float*)d_in[27];
    const float* bout = (const float*)d_in[28];

    float* ws   = (float*)d_ws;
    float* h1   = ws;                    // 512*7200
    float* h2   = h1 + 3686400;          // 512*1152
    float* feat = h2 + 589824;           // 512*128
    float* E2   = feat + 65536;          // 384
    float* w2t  = E2 + 384;              // 9216
    float* w3t  = w2t + 9216;            // 9216

    wprep_k<<<3, 384, 0, stream>>>(c2w, c3w, emb, Wxh, bh, w2t, w3t, E2);
    conv1_k<<<512, 512, 0, stream>>>(x, c1w, c1b, g1, b1, m1, v1, h1);
    conv2_k<<<512, 192, 0, stream>>>(h1, w2t, c2b, g2, b2, m2, v2, h2);
    conv3_k<<<512, 256, 0, stream>>>(h2, w3t, c3b, g3, b3, m3, v3, feat);
    router_k<<<512, 512, 0, stream>>>(feat, Whh, Who, bo, E2,
                                      Wexp, bexp, Wout, bout, (float*)d_out);
}

// Round 12
// 219.682 us; speedup vs baseline: 1.2993x; 1.2993x over previous
//
#include <hip/hip_runtime.h>
#include <math.h>

// ---------------- wprep: block0 = conv2 weight transpose, block1 = conv3, block2 = E2
__global__ __launch_bounds__(384) void wprep_k(
    const float* __restrict__ c2w, const float* __restrict__ c3w,
    const float* __restrict__ emb, const float* __restrict__ Wxh,
    const float* __restrict__ bh,
    float* __restrict__ w2t, float* __restrict__ w3t, float* __restrict__ E2)
{
    const int t = threadIdx.x, blk = blockIdx.x;
    if (blk == 0) {
        for (int i = t; i < 9216; i += 384) {
            const int co = i & 31, k = i >> 5;
            w2t[i] = c2w[co * 288 + k];
        }
    } else if (blk == 1) {
        for (int i = t; i < 9216; i += 384) {
            const int co = i & 31, k = i >> 5;
            w3t[i] = c3w[co * 288 + k];
        }
    } else {
        const int o = t >> 7, j = t & 127;
        float a = bh[j], a2 = 0.f;
        #pragma unroll 4
        for (int d = 0; d < 64; ++d) {
            a  += emb[o * 128 + d] * Wxh[d * 128 + j];
            a2 += emb[o * 128 + d + 64] * Wxh[(d + 64) * 128 + j];
        }
        E2[t] = a + a2;
    }
}

// ---------------- conv1: (512,1,32,32) -> conv3x3(32) -> BN -> ReLU -> pool2 -> h1 (512,32,15,15)
__global__ __launch_bounds__(512) void conv1_k(
    const float* __restrict__ x, const float* __restrict__ w,
    const float* __restrict__ cb, const float* __restrict__ bg,
    const float* __restrict__ bb, const float* __restrict__ bm,
    const float* __restrict__ bv, float* __restrict__ h1)
{
    __shared__ float img[32 * 33];
    __shared__ float ws_[288];
    __shared__ float scale[32], bias2[32];
    const int b = blockIdx.x, tid = threadIdx.x;
    for (int i = tid; i < 1024; i += 512) {
        const int y = i >> 5, xx = i & 31;
        img[y * 33 + xx] = x[b * 1024 + i];
    }
    if (tid < 288) ws_[tid] = w[tid];
    if (tid < 32) {
        float inv = bg[tid] / sqrtf(bv[tid] + 1e-5f);
        scale[tid] = inv;
        bias2[tid] = (cb[tid] - bm[tid]) * inv + bb[tid];
    }
    __syncthreads();

    const int co = tid >> 4, py = tid & 15;
    if (py < 15) {
        float acc0[30], acc1[30];
        #pragma unroll
        for (int i = 0; i < 30; ++i) { acc0[i] = 0.f; acc1[i] = 0.f; }
        const float* w9 = &ws_[co * 9];
        #pragma unroll
        for (int ir = 0; ir < 4; ++ir) {
            const int y = 2 * py + ir;
            float wk0 = 0.f, wk1 = 0.f, wk2 = 0.f, wl0 = 0.f, wl1 = 0.f, wl2 = 0.f;
            if (ir <= 2) { wk0 = w9[ir * 3 + 0]; wk1 = w9[ir * 3 + 1]; wk2 = w9[ir * 3 + 2]; }
            if (ir >= 1) { wl0 = w9[(ir - 1) * 3 + 0]; wl1 = w9[(ir - 1) * 3 + 1]; wl2 = w9[(ir - 1) * 3 + 2]; }
            #pragma unroll
            for (int xx = 0; xx < 32; ++xx) {
                const float rv = img[y * 33 + xx];
                if (ir <= 2) {
                    if (xx <= 29) acc0[xx] += rv * wk0;
                    if (xx >= 1 && xx <= 30) acc0[xx - 1] += rv * wk1;
                    if (xx >= 2) acc0[xx - 2] += rv * wk2;
                }
                if (ir >= 1) {
                    if (xx <= 29) acc1[xx] += rv * wl0;
                    if (xx >= 1 && xx <= 30) acc1[xx - 1] += rv * wl1;
                    if (xx >= 2) acc1[xx - 2] += rv * wl2;
                }
            }
        }
        const float sc = scale[co], bs = bias2[co];
        #pragma unroll
        for (int px = 0; px < 15; ++px) {
            const float v = fmaxf(acc0[2 * px] * sc + bs, 0.f)
                          + fmaxf(acc0[2 * px + 1] * sc + bs, 0.f)
                          + fmaxf(acc1[2 * px] * sc + bs, 0.f)
                          + fmaxf(acc1[2 * px + 1] * sc + bs, 0.f);
            h1[b * 7200 + co * 225 + py * 15 + px] = v * 0.25f;
        }
    }
}

// ---------------- fused conv2+conv3: h1 -> (conv2) h2 in LDS -> (conv3) feat (512,128)
__global__ __launch_bounds__(256) void conv23_k(
    const float* __restrict__ h1, const float* __restrict__ w2t,
    const float* __restrict__ c2b, const float* __restrict__ g2,
    const float* __restrict__ b2, const float* __restrict__ m2,
    const float* __restrict__ v2, const float* __restrict__ w3t,
    const float* __restrict__ c3b, const float* __restrict__ g3,
    const float* __restrict__ b3, const float* __restrict__ m3,
    const float* __restrict__ v3, float* __restrict__ feat)
{
    __shared__ float in_s[32 * 14 * 16];      // conv2 input, rows padded to 16
    __shared__ float h2s[32 * 48];            // conv2 output = conv3 input, [ci][6][8]
    __shared__ float psum[2][4][4][33];
    const int b = blockIdx.x, tid = threadIdx.x;
    for (int i = tid; i < 6720; i += 256) {
        const int ci = i / 210, rem = i % 210;
        const int row = rem / 15, col = rem % 15;
        in_s[ci * 224 + row * 16 + col] = h1[b * 7200 + ci * 225 + rem];
    }
    __syncthreads();

    // ---- conv2 (192 active threads: co = tid&31, py = tid>>5 in 0..5)
    if (tid < 192) {
        const int co = tid & 31, py = tid >> 5;
        float acc0[12], acc1[12];
        #pragma unroll
        for (int i = 0; i < 12; ++i) { acc0[i] = 0.f; acc1[i] = 0.f; }
        for (int ci = 0; ci < 32; ++ci) {
            float w9[9];
            const float* wk = &w2t[(ci * 9) * 32 + co];
            #pragma unroll
            for (int kk = 0; kk < 9; ++kk) w9[kk] = wk[kk * 32];
            #pragma unroll
            for (int ir = 0; ir < 4; ++ir) {
                const float* rp = &in_s[ci * 224 + (2 * py + ir) * 16];
                const float4 q0 = *reinterpret_cast<const float4*>(rp);
                const float4 q1 = *reinterpret_cast<const float4*>(rp + 4);
                const float4 q2 = *reinterpret_cast<const float4*>(rp + 8);
                const float4 q3 = *reinterpret_cast<const float4*>(rp + 12);
                float p[16];
                p[0]=q0.x; p[1]=q0.y; p[2]=q0.z; p[3]=q0.w;
                p[4]=q1.x; p[5]=q1.y; p[6]=q1.z; p[7]=q1.w;
                p[8]=q2.x; p[9]=q2.y; p[10]=q2.z; p[11]=q2.w;
                p[12]=q3.x; p[13]=q3.y; p[14]=q3.z; p[15]=q3.w;
                if (ir <= 2) {
                    const float wa0 = w9[ir * 3], wa1 = w9[ir * 3 + 1], wa2 = w9[ir * 3 + 2];
                    #pragma unroll
                    for (int c = 0; c < 12; ++c)
                        acc0[c] += p[c] * wa0 + p[c + 1] * wa1 + p[c + 2] * wa2;
                }
                if (ir >= 1) {
                    const float wb0 = w9[(ir - 1) * 3], wb1 = w9[(ir - 1) * 3 + 1], wb2 = w9[(ir - 1) * 3 + 2];
                    #pragma unroll
                    for (int c = 0; c < 12; ++c)
                        acc1[c] += p[c] * wb0 + p[c + 1] * wb1 + p[c + 2] * wb2;
                }
            }
        }
        const float inv = g2[co] / sqrtf(v2[co] + 1e-5f);
        const float bs = (c2b[co] - m2[co]) * inv + b2[co];
        #pragma unroll
        for (int px = 0; px < 6; ++px) {
            const float v = fmaxf(acc0[2 * px] * inv + bs, 0.f)
                          + fmaxf(acc0[2 * px + 1] * inv + bs, 0.f)
                          + fmaxf(acc1[2 * px] * inv + bs, 0.f)
                          + fmaxf(acc1[2 * px + 1] * inv + bs, 0.f);
            h2s[co * 48 + py * 8 + px] = v * 0.25f;
        }
    }
    __syncthreads();

    // ---- conv3 (all 256 threads: co = tid&31, g = tid>>5 -> pos, ci-half)
    {
        const int co = tid & 31, g = tid >> 5;
        const int pos = g & 3, h = g >> 2;
        const int y0 = (pos >> 1) * 2, x0 = (pos & 1) * 2;
        float s00 = 0.f, s01 = 0.f, s10 = 0.f, s11 = 0.f;
        for (int ci = h * 16; ci < h * 16 + 16; ++ci) {
            float w9[9];
            const float* wk = &w3t[(ci * 9) * 32 + co];
            #pragma unroll
            for (int kk = 0; kk < 9; ++kk) w9[kk] = wk[kk * 32];
            const int base = ci * 48 + y0 * 8 + x0;
            float p[4][4];
            #pragma unroll
            for (int i = 0; i < 4; ++i) {
                const float2 a = *reinterpret_cast<const float2*>(&h2s[base + i * 8]);
                const float2 c = *reinterpret_cast<const float2*>(&h2s[base + i * 8 + 2]);
                p[i][0] = a.x; p[i][1] = a.y; p[i][2] = c.x; p[i][3] = c.y;
            }
            #pragma unroll
            for (int ky = 0; ky < 3; ++ky)
                #pragma unroll
                for (int kx = 0; kx < 3; ++kx) {
                    const float wv = w9[ky * 3 + kx];
                    s00 += p[ky][kx] * wv;
                    s01 += p[ky][kx + 1] * wv;
                    s10 += p[ky + 1][kx] * wv;
                    s11 += p[ky + 1][kx + 1] * wv;
                }
        }
        psum[h][pos][0][co] = s00;
        psum[h][pos][1][co] = s01;
        psum[h][pos][2][co] = s10;
        psum[h][pos][3][co] = s11;
        __syncthreads();
        if (h == 0) {
            const float inv = g3[co] / sqrtf(v3[co] + 1e-5f);
            const float bs = (c3b[co] - m3[co]) * inv + b3[co];
            float v = 0.f;
            #pragma unroll
            for (int k = 0; k < 4; ++k) {
                const float sk = psum[0][pos][k][co] + psum[1][pos][k][co];
                v += fmaxf(sk * inv + bs, 0.f);
            }
            feat[b * 128 + co * 4 + pos] = v * 0.25f;
        }
    }
}

// ---------------- router v4 = round-8 structure + float4 LDS broadcasts
__global__ __launch_bounds__(512, 4) void router_k(
    const float* __restrict__ feat, const float* __restrict__ Whh,
    const float* __restrict__ Who, const float* __restrict__ bo,
    const float* __restrict__ E2, const float* __restrict__ Wexp,
    const float* __restrict__ bexp, const float* __restrict__ Wout,
    const float* __restrict__ bout, float* __restrict__ out)
{
    const int b = blockIdx.x, tid = threadIdx.x;
    const int j = tid & 127, q = tid >> 7;
    __shared__ __align__(16) float hbuf[2][8][128];
    __shared__ float E2s[3][128];
    __shared__ float bexps[3][128];
    __shared__ float psum[4][8][128];
    __shared__ float total[24], scores[8];
    __shared__ int bi[8], opsel[8], oph[3][8], oph2[3][8];

    const float fv = feat[b * 128 + j];
    hbuf[0][2 * q][j] = fv;
    hbuf[0][2 * q + 1][j] = fv;
    for (int i = tid; i < 384; i += 512) {
        (&E2s[0][0])[i] = E2[i];
        (&bexps[0][0])[i] = bexp[i];
    }
    if (tid < 8) scores[tid] = (tid == 0) ? 0.f : -1.0e9f;
    __syncthreads();

    const int dbase = q * 32;
    int cur = 0;
    for (int t = 0; t < 3; ++t) {
        // ---- logits + log_softmax(T=0.4)
        {
            const int grp = tid >> 5, l = tid & 31;
            if (grp < 8) {
                float p0 = 0.f, p1 = 0.f, p2 = 0.f;
                #pragma unroll
                for (int dd = 0; dd < 4; ++dd) {
                    const int d = l + 32 * dd;
                    const float hv = hbuf[cur][grp][d];
                    p0 += hv * Who[d * 3 + 0];
                    p1 += hv * Who[d * 3 + 1];
                    p2 += hv * Who[d * 3 + 2];
                }
                #pragma unroll
                for (int s = 16; s > 0; s >>= 1) {
                    p0 += __shfl_down(p0, s, 32);
                    p1 += __shfl_down(p1, s, 32);
                    p2 += __shfl_down(p2, s, 32);
                }
                if (l == 0) {
                    const float t0 = (p0 + bo[0]) / 0.4f;
                    const float t1 = (p1 + bo[1]) / 0.4f;
                    const float t2 = (p2 + bo[2]) / 0.4f;
                    const float mm = fmaxf(t0, fmaxf(t1, t2));
                    const float lse = mm + logf(expf(t0 - mm) + expf(t1 - mm) + expf(t2 - mm));
                    const float sc = scores[grp];
                    total[grp * 3 + 0] = sc + (t0 - lse);
                    total[grp * 3 + 1] = sc + (t1 - lse);
                    total[grp * 3 + 2] = sc + (t2 - lse);
                }
            }
        }
        __syncthreads();
        // ---- stable top-8 (first-index-wins = lax.top_k)
        if (tid == 0) {
            float tv[24];
            #pragma unroll
            for (int i = 0; i < 24; ++i) tv[i] = total[i];
            unsigned mask = 0;
            for (int r = 0; r < 8; ++r) {
                float best = -INFINITY; int idx = 0;
                #pragma unroll
                for (int i = 0; i < 24; ++i) {
                    if (!(mask & (1u << i)) && tv[i] > best) { best = tv[i]; idx = i; }
                }
                mask |= 1u << idx;
                scores[r] = best;
                bi[r] = idx / 3;
                opsel[r] = idx % 3;
            }
            for (int r = 0; r < 8; ++r) {
                for (int s = 0; s < t; ++s) oph2[s][r] = oph[s][bi[r]];
                oph2[t][r] = opsel[r];
            }
            for (int r = 0; r < 8; ++r)
                for (int s = 0; s <= t; ++s) oph[s][r] = oph2[s][r];
        }
        __syncthreads();
        // ---- beam GEMV: float4 uniform (broadcast) LDS reads; one Whh stream feeds 8 beams
        {
            const float* h0p = &hbuf[cur][bi[0]][dbase];
            const float* h1p = &hbuf[cur][bi[1]][dbase];
            const float* h2p = &hbuf[cur][bi[2]][dbase];
            const float* h3p = &hbuf[cur][bi[3]][dbase];
            const float* h4p = &hbuf[cur][bi[4]][dbase];
            const float* h5p = &hbuf[cur][bi[5]][dbase];
            const float* h6p = &hbuf[cur][bi[6]][dbase];
            const float* h7p = &hbuf[cur][bi[7]][dbase];
            float a0 = 0.f, a1 = 0.f, a2 = 0.f, a3 = 0.f, a4 = 0.f, a5 = 0.f, a6 = 0.f, a7 = 0.f;
            const float* wp = &Whh[dbase * 128 + j];
            #pragma unroll
            for (int dv = 0; dv < 8; ++dv) {
                const float4 x0 = *reinterpret_cast<const float4*>(h0p + 4 * dv);
                const float4 x1 = *reinterpret_cast<const float4*>(h1p + 4 * dv);
                const float4 x2 = *reinterpret_cast<const float4*>(h2p + 4 * dv);
                const float4 x3 = *reinterpret_cast<const float4*>(h3p + 4 * dv);
                const float4 x4 = *reinterpret_cast<const float4*>(h4p + 4 * dv);
                const float4 x5 = *reinterpret_cast<const float4*>(h5p + 4 * dv);
                const float4 x6 = *reinterpret_cast<const float4*>(h6p + 4 * dv);
                const float4 x7 = *reinterpret_cast<const float4*>(h7p + 4 * dv);
                const float wv0 = wp[(4 * dv + 0) * 128];
                const float wv1 = wp[(4 * dv + 1) * 128];
                const float wv2 = wp[(4 * dv + 2) * 128];
                const float wv3 = wp[(4 * dv + 3) * 128];
                a0 += x0.x * wv0 + x0.y * wv1 + x0.z * wv2 + x0.w * wv3;
                a1 += x1.x * wv0 + x1.y * wv1 + x1.z * wv2 + x1.w * wv3;
                a2 += x2.x * wv0 + x2.y * wv1 + x2.z * wv2 + x2.w * wv3;
                a3 += x3.x * wv0 + x3.y * wv1 + x3.z * wv2 + x3.w * wv3;
                a4 += x4.x * wv0 + x4.y * wv1 + x4.z * wv2 + x4.w * wv3;
                a5 += x5.x * wv0 + x5.y * wv1 + x5.z * wv2 + x5.w * wv3;
                a6 += x6.x * wv0 + x6.y * wv1 + x6.z * wv2 + x6.w * wv3;
                a7 += x7.x * wv0 + x7.y * wv1 + x7.z * wv2 + x7.w * wv3;
            }
            psum[q][0][j] = a0; psum[q][1][j] = a1; psum[q][2][j] = a2; psum[q][3][j] = a3;
            psum[q][4][j] = a4; psum[q][5][j] = a5; psum[q][6][j] = a6; psum[q][7][j] = a7;
        }
        __syncthreads();
        {
            const int nxt = cur ^ 1;
            #pragma unroll
            for (int rr = 0; rr < 2; ++rr) {
                const int r = 2 * q + rr;
                const float v = psum[0][r][j] + psum[1][r][j] + psum[2][r][j] + psum[3][r][j]
                              + E2s[opsel[r]][j];
                hbuf[nxt][r][j] = tanhf(v);
            }
        }
        cur ^= 1;
        __syncthreads();
    }

    // ---- expert chain: 3 dedup'd weight streams + per-beam select; float4 h broadcasts
    hbuf[0][2 * q][j] = fv;
    hbuf[0][2 * q + 1][j] = fv;
    __syncthreads();
    int c2 = 0;
    for (int t = 0; t < 3; ++t) {
        const int o0 = oph[t][0], o1 = oph[t][1], o2 = oph[t][2], o3 = oph[t][3];
        const int o4 = oph[t][4], o5 = oph[t][5], o6 = oph[t][6], o7 = oph[t][7];
        {
            const float* h0p = &hbuf[c2][0][dbase];
            const float* h1p = &hbuf[c2][1][dbase];
            const float* h2p = &hbuf[c2][2][dbase];
            const float* h3p = &hbuf[c2][3][dbase];
            const float* h4p = &hbuf[c2][4][dbase];
            const float* h5p = &hbuf[c2][5][dbase];
            const float* h6p = &hbuf[c2][6][dbase];
            const float* h7p = &hbuf[c2][7][dbase];
            float a0 = 0.f, a1 = 0.f, a2 = 0.f, a3 = 0.f, a4 = 0.f, a5 = 0.f, a6 = 0.f, a7 = 0.f;
            const float* wp = &Wexp[dbase * 128 + j];
            #pragma unroll
            for (int dv = 0; dv < 8; ++dv) {
                const float4 x0 = *reinterpret_cast<const float4*>(h0p + 4 * dv);
                const float4 x1 = *reinterpret_cast<const float4*>(h1p + 4 * dv);
                const float4 x2 = *reinterpret_cast<const float4*>(h2p + 4 * dv);
                const float4 x3 = *reinterpret_cast<const float4*>(h3p + 4 * dv);
                const float4 x4 = *reinterpret_cast<const float4*>(h4p + 4 * dv);
                const float4 x5 = *reinterpret_cast<const float4*>(h5p + 4 * dv);
                const float4 x6 = *reinterpret_cast<const float4*>(h6p + 4 * dv);
                const float4 x7 = *reinterpret_cast<const float4*>(h7p + 4 * dv);
                #pragma unroll
                for (int e = 0; e < 4; ++e) {
                    const int d = 4 * dv + e;
                    const float w0 = wp[d * 128];
                    const float w1 = wp[d * 128 + 16384];
                    const float w2 = wp[d * 128 + 32768];
                    const float he0 = (e == 0) ? x0.x : (e == 1) ? x0.y : (e == 2) ? x0.z : x0.w;
                    const float he1 = (e == 0) ? x1.x : (e == 1) ? x1.y : (e == 2) ? x1.z : x1.w;
                    const float he2 = (e == 0) ? x2.x : (e == 1) ? x2.y : (e == 2) ? x2.z : x2.w;
                    const float he3 = (e == 0) ? x3.x : (e == 1) ? x3.y : (e == 2) ? x3.z : x3.w;
                    const float he4 = (e == 0) ? x4.x : (e == 1) ? x4.y : (e == 2) ? x4.z : x4.w;
                    const float he5 = (e == 0) ? x5.x : (e == 1) ? x5.y : (e == 2) ? x5.z : x5.w;
                    const float he6 = (e == 0) ? x6.x : (e == 1) ? x6.y : (e == 2) ? x6.z : x6.w;
                    const float he7 = (e == 0) ? x7.x : (e == 1) ? x7.y : (e == 2) ? x7.z : x7.w;
                    a0 += he0 * (o0 == 2 ? w2 : (o0 == 1 ? w1 : w0));
                    a1 += he1 * (o1 == 2 ? w2 : (o1 == 1 ? w1 : w0));
                    a2 += he2 * (o2 == 2 ? w2 : (o2 == 1 ? w1 : w0));
                    a3 += he3 * (o3 == 2 ? w2 : (o3 == 1 ? w1 : w0));
                    a4 += he4 * (o4 == 2 ? w2 : (o4 == 1 ? w1 : w0));
                    a5 += he5 * (o5 == 2 ? w2 : (o5 == 1 ? w1 : w0));
                    a6 += he6 * (o6 == 2 ? w2 : (o6 == 1 ? w1 : w0));
                    a7 += he7 * (o7 == 2 ? w2 : (o7 == 1 ? w1 : w0));
                }
            }
            psum[q][0][j] = a0; psum[q][1][j] = a1; psum[q][2][j] = a2; psum[q][3][j] = a3;
            psum[q][4][j] = a4; psum[q][5][j] = a5; psum[q][6][j] = a6; psum[q][7][j] = a7;
        }
        __syncthreads();
        {
            const int nxt = c2 ^ 1;
            #pragma unroll
            for (int rr = 0; rr < 2; ++rr) {
                const int r = 2 * q + rr;
                const float v = psum[0][r][j] + psum[1][r][j] + psum[2][r][j] + psum[3][r][j]
                              + bexps[oph[t][r]][j];
                hbuf[nxt][r][j] = fmaxf(v, 0.f);
            }
        }
        c2 ^= 1;
        __syncthreads();
    }

    // ---- out = log_softmax(hs @ Wout + bout)
    {
        const int grp = tid >> 5, l = tid & 31;
        if (grp < 8) {
            float acc = 0.f;
            if (l < 10) {
                acc = bout[l];
                float acc2 = 0.f;
                const float* hrow = &hbuf[c2][grp][0];
                #pragma unroll 4
                for (int d = 0; d < 64; ++d) {
                    acc  += hrow[d] * Wout[d * 10 + l];
                    acc2 += hrow[d + 64] * Wout[(d + 64) * 10 + l];
                }
                acc += acc2;
            }
            float mm = (l < 10) ? acc : -INFINITY;
            #pragma unroll
            for (int s = 16; s > 0; s >>= 1) mm = fmaxf(mm, __shfl_xor(mm, s, 32));
            float ex = (l < 10) ? expf(acc - mm) : 0.f;
            float sum = ex;
            #pragma unroll
            for (int s = 16; s > 0; s >>= 1) sum += __shfl_xor(sum, s, 32);
            const float lse = mm + logf(sum);
            if (l < 10) out[(b * 8 + grp) * 10 + l] = acc - lse;
        }
    }
}

extern "C" void kernel_launch(void* const* d_in, const int* in_sizes, int n_in,
                              void* d_out, int out_size, void* d_ws, size_t ws_size,
                              hipStream_t stream) {
    (void)in_sizes; (void)n_in; (void)out_size; (void)ws_size;
    const float* x    = (const float*)d_in[0];
    const float* c1w  = (const float*)d_in[1];
    const float* c1b  = (const float*)d_in[2];
    const float* g1   = (const float*)d_in[3];
    const float* b1   = (const float*)d_in[4];
    const float* m1   = (const float*)d_in[5];
    const float* v1   = (const float*)d_in[6];
    const float* c2w  = (const float*)d_in[7];
    const float* c2b  = (const float*)d_in[8];
    const float* g2   = (const float*)d_in[9];
    const float* b2   = (const float*)d_in[10];
    const float* m2   = (const float*)d_in[11];
    const float* v2   = (const float*)d_in[12];
    const float* c3w  = (const float*)d_in[13];
    const float* c3b  = (const float*)d_in[14];
    const float* g3   = (const float*)d_in[15];
    const float* b3   = (const float*)d_in[16];
    const float* m3   = (const float*)d_in[17];
    const float* v3   = (const float*)d_in[18];
    const float* Wxh  = (const float*)d_in[19];
    const float* Whh  = (const float*)d_in[20];
    const float* bh   = (const float*)d_in[21];
    const float* Who  = (const float*)d_in[22];
    const float* bo   = (const float*)d_in[23];
    const float* emb  = (const float*)d_in[24];
    const float* Wexp = (const float*)d_in[25];
    const float* bexp = (const float*)d_in[26];
    const float* Wout = (const float*)d_in[27];
    const float* bout = (const float*)d_in[28];

    float* ws   = (float*)d_ws;
    float* h1   = ws;                    // 512*7200
    float* feat = h1 + 3686400;          // 512*128
    float* E2   = feat + 65536;          // 384
    float* w2t  = E2 + 384;              // 9216
    float* w3t  = w2t + 9216;            // 9216

    wprep_k<<<3, 384, 0, stream>>>(c2w, c3w, emb, Wxh, bh, w2t, w3t, E2);
    conv1_k<<<512, 512, 0, stream>>>(x, c1w, c1b, g1, b1, m1, v1, h1);
    conv23_k<<<512, 256, 0, stream>>>(h1, w2t, c2b, g2, b2, m2, v2,
                                      w3t, c3b, g3, b3, m3, v3, feat);
    router_k<<<512, 512, 0, stream>>>(feat, Whh, Who, bo, E2,
                                      Wexp, bexp, Wout, bout, (float*)d_out);
}